// Round 2
// baseline (712.777 us; speedup 1.0000x reference)
//
#include <hip/hip_runtime.h>

// LIF recurrence, chunked over T with 160-step warm-up replay (alpha^160=3.4e-4,
// threshold 1.75e-2; R0 measured absmax 3.9e-3 at W=160 -> keep W=160).
// R1: float2 lanes (8B transactions), 8 chunks -> 512 blocks = 2 blocks/CU,
// alternating A/B register double-buffer (no copy -> fine-grained vmcnt),
// nontemporal stores for the 512MB streaming output.

typedef float v2 __attribute__((ext_vector_type(2)));

constexpr int T_STEPS = 2048;
constexpr int N_NEUR  = 32768;
constexpr int N2      = N_NEUR / 2;        // float2 columns: 16384
constexpr int NCHUNK  = 8;
constexpr int CHUNK   = T_STEPS / NCHUNK;  // 256 steps per chunk
constexpr int WARM    = 160;               // warm-up steps (multiple of 2*U)
constexpr int U       = 8;                 // group size (prefetch granularity)

__device__ __forceinline__ void lif_step(v2& v, v2 c, v2& s) {
    const float ALPHA = (float)0.95122942450071400909;        // f32(exp(-1/20))
    const float BETA  = (float)(1.0 - 0.95122942450071400909);// f32(1-alpha_f64)
    v = ALPHA * v + BETA * c;
    s.x = (v.x >= 1.0f) ? 1.0f : 0.0f;
    s.y = (v.y >= 1.0f) ? 1.0f : 0.0f;
    v.x = (v.x >= 1.0f) ? 0.0f : v.x;
    v.y = (v.y >= 1.0f) ? 0.0f : v.y;
}

__global__ __launch_bounds__(256) void lif_v2(
    const v2* __restrict__ cur, const v2* __restrict__ v0,
    v2* __restrict__ spikes, v2* __restrict__ volts)
{
    const int n     = blockIdx.x * blockDim.x + threadIdx.x;  // float2 column
    const int chunk = blockIdx.y;
    const int t0    = chunk * CHUNK;

    v2 v;
    v2 A[U], B[U];

    if (chunk == 0) {
        v = v0[n];
    } else {
        v.x = 0.0f; v.y = 0.0f;
        // ---- warm-up: WARM steps, pipelined, no stores ----
        const v2* q = cur + (size_t)(t0 - WARM) * N2 + n;
        constexpr int GW = WARM / U;   // 20 (even)
        #pragma unroll
        for (int i = 0; i < U; ++i) A[i] = q[(size_t)i * N2];
        q += (size_t)U * N2;
        for (int g = 0; g < GW; g += 2) {
            if (g + 1 < GW) {
                #pragma unroll
                for (int i = 0; i < U; ++i) B[i] = q[(size_t)i * N2];
                q += (size_t)U * N2;
            }
            v2 s;
            #pragma unroll
            for (int i = 0; i < U; ++i) lif_step(v, A[i], s);
            if (g + 2 < GW) {
                #pragma unroll
                for (int i = 0; i < U; ++i) A[i] = q[(size_t)i * N2];
                q += (size_t)U * N2;
            }
            if (g + 1 < GW) {
                #pragma unroll
                for (int i = 0; i < U; ++i) lif_step(v, B[i], s);
            }
        }
    }

    // ---- main chunk: CHUNK steps with alternating double-buffer ----
    const v2* p = cur + (size_t)t0 * N2 + n;
    size_t idx = (size_t)t0 * N2 + n;
    constexpr int G = CHUNK / U;       // 32 (even)

    #pragma unroll
    for (int i = 0; i < U; ++i) A[i] = p[(size_t)i * N2];
    p += (size_t)U * N2;

    for (int g = 0; g < G; g += 2) {
        // prefetch group g+1 into B (always valid: G even, g+1 <= G-1)
        #pragma unroll
        for (int i = 0; i < U; ++i) B[i] = p[(size_t)i * N2];
        p += (size_t)U * N2;
        // compute + store group g from A
        #pragma unroll
        for (int i = 0; i < U; ++i) {
            v2 s;
            lif_step(v, A[i], s);
            __builtin_nontemporal_store(s, &spikes[idx]);
            __builtin_nontemporal_store(v, &volts[idx]);
            idx += N2;
        }
        // prefetch group g+2 into A (skip on last pair)
        if (g + 2 < G) {
            #pragma unroll
            for (int i = 0; i < U; ++i) A[i] = p[(size_t)i * N2];
            p += (size_t)U * N2;
        }
        // compute + store group g+1 from B
        #pragma unroll
        for (int i = 0; i < U; ++i) {
            v2 s;
            lif_step(v, B[i], s);
            __builtin_nontemporal_store(s, &spikes[idx]);
            __builtin_nontemporal_store(v, &volts[idx]);
            idx += N2;
        }
    }
}

extern "C" void kernel_launch(void* const* d_in, const int* in_sizes, int n_in,
                              void* d_out, int out_size, void* d_ws, size_t ws_size,
                              hipStream_t stream) {
    const v2* cur = (const v2*)d_in[0];   // (T, N) fp32 viewed as (T, N/2) float2
    const v2* v0  = (const v2*)d_in[1];   // (N,) fp32 as (N/2,) float2
    v2* spikes = (v2*)d_out;                               // (T, N/2)
    v2* volts  = (v2*)d_out + (size_t)T_STEPS * N2;        // (T, N/2)

    dim3 block(256);
    dim3 grid(N2 / 256, NCHUNK);          // 64 x 8 = 512 blocks
    lif_v2<<<grid, block, 0, stream>>>(cur, v0, spikes, volts);
}